// Round 1
// baseline (1346.551 us; speedup 1.0000x reference)
//
#include <hip/hip_runtime.h>
#include <hip/hip_bf16.h>

// Problem constants
constexpr int B_    = 2048;
constexpr int NIN   = 256;
constexpr int H_    = 128;
constexpr int RANK_ = 8;
constexpr float EPS_ = 1e-5f;

constexpr int PC = 8;          // p-chunk size per quad block
constexpr int NCHUNK = H_ / PC; // 16 chunks
constexpr int BT = 64;         // batch tile per quad block

// ---------------------------------------------------------------------------
// init: zero Y accumulator and BN-stat accumulators (ws is poisoned 0xAA)
__global__ void k_init(float* __restrict__ Y, float* __restrict__ stats) {
    int i = blockIdx.x * 256 + threadIdx.x;
    if (i < B_ * H_) Y[i] = 0.f;
    if (i < (RANK_ + 1) * 256) stats[i] = 0.f;
}

// ---------------------------------------------------------------------------
// Z = relu(X@W1+b1); R2 = relu(X@W2+b2); Zi = Z.  One block per batch row.
__global__ void k_in_proj(const float* __restrict__ X,
                          const float* __restrict__ W1, const float* __restrict__ b1,
                          const float* __restrict__ W2, const float* __restrict__ b2,
                          float* __restrict__ Z, float* __restrict__ Zi,
                          float* __restrict__ R2) {
    __shared__ float sx[NIN];
    const int b = blockIdx.x, t = threadIdx.x;
    sx[t]        = X[b * NIN + t];
    sx[t + H_]   = X[b * NIN + H_ + t];
    __syncthreads();
    float s1 = 0.f, s2 = 0.f;
#pragma unroll 8
    for (int i = 0; i < NIN; ++i) {
        const float x = sx[i];
        s1 = fmaf(x, W1[i * H_ + t], s1);
        s2 = fmaf(x, W2[i * H_ + t], s2);
    }
    const float z = fmaxf(s1 + b1[t], 0.f);
    const float r = fmaxf(s2 + b2[t], 0.f);
    Z[b * H_ + t]  = z;
    Zi[b * H_ + t] = z;
    R2[b * H_ + t] = r;
}

// ---------------------------------------------------------------------------
// Quadratic: Tpart[chunk][b][k] = sum_{p in chunk, q} Zi[b,p] * P[p,q,k] * Z[b,q]
// grid (32 b-tiles, 16 p-chunks), block 256.  Thread owns 4b x 8k accumulators.
__global__ __launch_bounds__(256, 2)
void k_quad(const float* __restrict__ Pr,   // P + rank*H^3
            const float* __restrict__ Z, const float* __restrict__ Zi,
            float* __restrict__ Tpart) {
    __shared__ float sZ[BT * 130];          // padded: bank-conflict-free
    __shared__ float sZi[BT * (PC + 1)];

    const int bx = blockIdx.x;     // batch tile
    const int pc = blockIdx.y;     // p chunk
    const int t  = threadIdx.x;
    const int b0 = bx * BT;

    // stage Z tile (64x128) — fully coalesced
#pragma unroll
    for (int i = 0; i < (BT * H_) / 256; ++i) {   // 32 iters
        const int e = i * 256 + t;
        const int r = e >> 7, c = e & 127;
        sZ[r * 130 + c] = Z[(size_t)(b0 + r) * H_ + c];
    }
    // stage Zi tile (64 x PC)
#pragma unroll
    for (int i = 0; i < (BT * PC) / 256; ++i) {   // 2 iters
        const int e = i * 256 + t;
        const int r = e / PC, c = e % PC;
        sZi[r * (PC + 1) + c] = Zi[(size_t)(b0 + r) * H_ + pc * PC + c];
    }
    __syncthreads();

    const int kg = t & 15;         // 16 k-groups of 8
    const int bg = t >> 4;         // 16 b-groups of 4
    const int k0 = kg * 8;
    const int bb = bg * 4;

    float acc[4][8];
#pragma unroll
    for (int j = 0; j < 4; ++j)
#pragma unroll
        for (int kk = 0; kk < 8; ++kk) acc[j][kk] = 0.f;

    for (int pi = 0; pi < PC; ++pi) {
        const float a0 = sZi[(bb + 0) * (PC + 1) + pi];
        const float a1 = sZi[(bb + 1) * (PC + 1) + pi];
        const float a2 = sZi[(bb + 2) * (PC + 1) + pi];
        const float a3 = sZi[(bb + 3) * (PC + 1) + pi];
        const float* Pp = Pr + (((size_t)(pc * PC + pi)) << 14) + k0;  // p*H*H + k0
#pragma unroll 4
        for (int q = 0; q < 128; ++q) {
            const float* pq = Pp + ((size_t)q << 7);
            float pv[8];
            *(float4*)(pv)     = *(const float4*)(pq);
            *(float4*)(pv + 4) = *(const float4*)(pq + 4);
            const float m0 = a0 * sZ[(bb + 0) * 130 + q];
            const float m1 = a1 * sZ[(bb + 1) * 130 + q];
            const float m2 = a2 * sZ[(bb + 2) * 130 + q];
            const float m3 = a3 * sZ[(bb + 3) * 130 + q];
#pragma unroll
            for (int kk = 0; kk < 8; ++kk) {
                const float pk = pv[kk];
                acc[0][kk] = fmaf(m0, pk, acc[0][kk]);
                acc[1][kk] = fmaf(m1, pk, acc[1][kk]);
                acc[2][kk] = fmaf(m2, pk, acc[2][kk]);
                acc[3][kk] = fmaf(m3, pk, acc[3][kk]);
            }
        }
    }

    // write partials
#pragma unroll
    for (int j = 0; j < 4; ++j) {
        float* Tp = Tpart + ((size_t)pc * B_ + (b0 + bb + j)) * H_ + k0;
        float4 v0 = {acc[j][0], acc[j][1], acc[j][2], acc[j][3]};
        float4 v1 = {acc[j][4], acc[j][5], acc[j][6], acc[j][7]};
        *(float4*)(Tp)     = v0;
        *(float4*)(Tp + 4) = v1;
    }
}

// ---------------------------------------------------------------------------
// Sum chunk partials -> T, accumulate column sum/sumsq into stats (atomics).
__global__ void k_reduce_stats(const float* __restrict__ Tpart,
                               float* __restrict__ T, float* __restrict__ stats) {
    const int t = threadIdx.x;
    const int k = t & 127, half = t >> 7;
    const int r0 = blockIdx.x * 32;
    float sum = 0.f, ssq = 0.f;
    for (int i = half; i < 32; i += 2) {
        const int b = r0 + i;
        float v = 0.f;
#pragma unroll
        for (int c = 0; c < NCHUNK; ++c)
            v += Tpart[((size_t)c * B_ + b) * H_ + k];
        T[(size_t)b * H_ + k] = v;
        sum += v;
        ssq += v * v;
    }
    __shared__ float ssum[256], sssq[256];
    ssum[t] = sum; sssq[t] = ssq;
    __syncthreads();
    if (half == 0) {
        atomicAdd(&stats[k],       ssum[t] + ssum[t + 128]);
        atomicAdd(&stats[128 + k], sssq[t] + sssq[t + 128]);
    }
}

// ---------------------------------------------------------------------------
// BN apply (training-mode, biased var) -> new Zi; Y += Zi/RANK
__global__ void k_bn_apply(const float* __restrict__ T, const float* __restrict__ stats,
                           const float* __restrict__ g, const float* __restrict__ bta,
                           float* __restrict__ Zi, float* __restrict__ Y) {
    const int i = blockIdx.x * 256 + threadIdx.x;
    const int k = i & 127;
    const float m  = stats[k] * (1.f / B_);
    const float v  = stats[128 + k] * (1.f / B_) - m * m;
    const float rs = rsqrtf(v + EPS_);
    const float z  = (T[i] - m) * rs * g[k] + bta[k];
    Zi[i] = z;
    Y[i] += z * (1.f / RANK_);
}

// ---------------------------------------------------------------------------
// column stats of a (B,H) matrix (for final BN over Y)
__global__ void k_colstats(const float* __restrict__ A, float* __restrict__ stats) {
    const int t = threadIdx.x;
    const int k = t & 127, half = t >> 7;
    const int r0 = blockIdx.x * 32;
    float sum = 0.f, ssq = 0.f;
    for (int i = half; i < 32; i += 2) {
        const float v = A[(size_t)(r0 + i) * H_ + k];
        sum += v; ssq += v * v;
    }
    __shared__ float ssum[256], sssq[256];
    ssum[t] = sum; sssq[t] = ssq;
    __syncthreads();
    if (half == 0) {
        atomicAdd(&stats[k],       ssum[t] + ssum[t + 128]);
        atomicAdd(&stats[128 + k], sssq[t] + sssq[t + 128]);
    }
}

// ---------------------------------------------------------------------------
// out = relu(relu(BN(Y)@W3 + b3) + R2)
__global__ void k_out(const float* __restrict__ Y, const float* __restrict__ ystats,
                      const float* __restrict__ gy, const float* __restrict__ by,
                      const float* __restrict__ W3, const float* __restrict__ b3,
                      const float* __restrict__ R2, float* __restrict__ out) {
    __shared__ float sy[H_];
    const int b = blockIdx.x, t = threadIdx.x;
    const float m  = ystats[t] * (1.f / B_);
    const float v  = ystats[128 + t] * (1.f / B_) - m * m;
    const float rs = rsqrtf(v + EPS_);
    sy[t] = (Y[(size_t)b * H_ + t] - m) * rs * gy[t] + by[t];
    __syncthreads();
    float s = 0.f;
#pragma unroll 8
    for (int h = 0; h < H_; ++h)
        s = fmaf(sy[h], W3[h * H_ + t], s);
    const float r = fmaxf(s + b3[t], 0.f) + R2[(size_t)b * H_ + t];
    out[(size_t)b * H_ + t] = fmaxf(r, 0.f);
}

// ---------------------------------------------------------------------------
extern "C" void kernel_launch(void* const* d_in, const int* in_sizes, int n_in,
                              void* d_out, int out_size, void* d_ws, size_t ws_size,
                              hipStream_t stream) {
    const float* X  = (const float*)d_in[0];
    const float* W1 = (const float*)d_in[1];
    const float* b1 = (const float*)d_in[2];
    const float* W2 = (const float*)d_in[3];
    const float* b2 = (const float*)d_in[4];
    const float* W3 = (const float*)d_in[5];
    const float* b3 = (const float*)d_in[6];
    const float* P  = (const float*)d_in[7];
    const float* gz = (const float*)d_in[8];
    const float* bz = (const float*)d_in[9];
    const float* gy = (const float*)d_in[10];
    const float* by = (const float*)d_in[11];
    float* out = (float*)d_out;

    float* ws    = (float*)d_ws;
    float* Tpart = ws;                                   // NCHUNK*B*H = 4,194,304
    float* T     = Tpart + (size_t)NCHUNK * B_ * H_;     // 262144
    float* Z     = T  + (size_t)B_ * H_;
    float* Zi    = Z  + (size_t)B_ * H_;
    float* R2    = Zi + (size_t)B_ * H_;
    float* Y     = R2 + (size_t)B_ * H_;
    float* stats = Y  + (size_t)B_ * H_;                 // (RANK+1)*256 floats

    k_init<<<(B_ * H_ + 255) / 256, 256, 0, stream>>>(Y, stats);
    k_in_proj<<<B_, H_, 0, stream>>>(X, W1, b1, W2, b2, Z, Zi, R2);

    for (int r = 0; r < RANK_; ++r) {
        const float* Pr = P + (size_t)r * H_ * H_ * H_;
        k_quad<<<dim3(B_ / BT, NCHUNK), 256, 0, stream>>>(Pr, Z, Zi, Tpart);
        k_reduce_stats<<<64, 256, 0, stream>>>(Tpart, T, stats + r * 256);
        k_bn_apply<<<(B_ * H_) / 256, 256, 0, stream>>>(T, stats + r * 256, gz, bz, Zi, Y);
    }

    k_colstats<<<64, 256, 0, stream>>>(Y, stats + RANK_ * 256);
    k_out<<<B_, H_, 0, stream>>>(Y, stats + RANK_ * 256, gy, by, W3, b3, R2, out);
}

// Round 2
// 444.190 us; speedup vs baseline: 3.0315x; 3.0315x over previous
//
#include <hip/hip_runtime.h>

typedef __bf16 bf16x8 __attribute__((ext_vector_type(8)));
typedef float  floatx4 __attribute__((ext_vector_type(4)));

constexpr int B_    = 2048;
constexpr int NIN   = 256;
constexpr int H_    = 128;
constexpr int RANK_ = 8;
constexpr float EPS_ = 1e-5f;

// ---------------------------------------------------------------------------
// init: zero Y, T (atomic target), stats
__global__ void k_init(float* __restrict__ Y, float* __restrict__ T,
                       float* __restrict__ stats) {
    int i = blockIdx.x * 256 + threadIdx.x;
    if (i < B_ * H_) { Y[i] = 0.f; T[i] = 0.f; }
    if (i < (RANK_ + 1) * 256) stats[i] = 0.f;
}

// ---------------------------------------------------------------------------
// Z = relu(X@W1+b1); R2 = relu(X@W2+b2); Zi = Z; Zbf = bf16(Z)
__global__ void k_in_proj(const float* __restrict__ X,
                          const float* __restrict__ W1, const float* __restrict__ b1,
                          const float* __restrict__ W2, const float* __restrict__ b2,
                          float* __restrict__ Z, float* __restrict__ Zi,
                          float* __restrict__ R2, __bf16* __restrict__ Zbf) {
    __shared__ float sx[NIN];
    const int b = blockIdx.x, t = threadIdx.x;
    sx[t]      = X[b * NIN + t];
    sx[t + H_] = X[b * NIN + H_ + t];
    __syncthreads();
    float s1 = 0.f, s2 = 0.f;
#pragma unroll 8
    for (int i = 0; i < NIN; ++i) {
        const float x = sx[i];
        s1 = fmaf(x, W1[i * H_ + t], s1);
        s2 = fmaf(x, W2[i * H_ + t], s2);
    }
    const float z = fmaxf(s1 + b1[t], 0.f);
    const float r = fmaxf(s2 + b2[t], 0.f);
    Z[b * H_ + t]   = z;
    Zi[b * H_ + t]  = z;
    R2[b * H_ + t]  = r;
    Zbf[b * H_ + t] = (__bf16)z;
}

// ---------------------------------------------------------------------------
// Convert one rank's P[p][q][k] (fp32) into MFMA-B-fragment-ordered bf16.
// dst elem index: (((p*4 + s)*8 + c)*64 + L)*8 + j  holds P[p][s*32+(L>>4)*8+j][c*16+(L&15)]
// grid: 128 blocks (p), 256 threads.
__global__ void k_pconv(const float* __restrict__ Psrc, __bf16* __restrict__ dst) {
    const int p = blockIdx.x, t = threadIdx.x;
    const int s = t >> 6, L = t & 63, quad = L >> 4, lo = L & 15;
    const float* Pp = Psrc + (size_t)p * (H_ * H_);
    __bf16* dp = dst + (size_t)p * (H_ * H_);
#pragma unroll
    for (int c = 0; c < 8; ++c) {
        __bf16 v[8];
#pragma unroll
        for (int j = 0; j < 8; ++j) {
            const int q = s * 32 + quad * 8 + j;
            const int k = c * 16 + lo;
            v[j] = (__bf16)Pp[q * H_ + k];
        }
        *(bf16x8*)(dp + (((size_t)(s * 8 + c)) * 64 + L) * 8) = *(const bf16x8*)v;
    }
}

// ---------------------------------------------------------------------------
// Quadratic via MFMA: T[b,k] += sum_{p in group} Zi[b,p] * (Z @ P[p])[b,k]
// grid (64 m-tiles of 32 rows, 8 p-groups of 16), block 256 (4 waves).
// Wave w covers cols [w*32, w*32+32); all waves share the block's 32 rows.
__global__ __launch_bounds__(256, 2)
void k_quad_mfma(const __bf16* __restrict__ Pperm,   // rank-base, frag-ordered
                 const __bf16* __restrict__ Zbf,
                 const float* __restrict__ Zi,
                 float* __restrict__ T) {
    const int mx = blockIdx.x;          // 64 row-tiles
    const int pg = blockIdx.y;          // 8 p-groups
    const int t  = threadIdx.x;
    const int w  = t >> 6, L = t & 63;
    const int quad = L >> 4, lo = L & 15;
    const int b0 = mx * 32;

    __shared__ float sZiT[16][32];      // [p-local][row]
    for (int e = t; e < 512; e += 256) {
        const int pp = e & 15, row = e >> 4;
        sZiT[pp][row] = Zi[(size_t)(b0 + row) * H_ + pg * 16 + pp];
    }

    // A-frags (Z rows, bf16) — p-invariant, register-resident.
    bf16x8 A[2][4];
#pragma unroll
    for (int mt = 0; mt < 2; ++mt)
#pragma unroll
        for (int ks = 0; ks < 4; ++ks)
            A[mt][ks] = *(const bf16x8*)(Zbf + (size_t)(b0 + mt * 16 + lo) * H_ + ks * 32 + quad * 8);
    __syncthreads();

    floatx4 acc[2][2];
#pragma unroll
    for (int mt = 0; mt < 2; ++mt)
#pragma unroll
        for (int nt = 0; nt < 2; ++nt)
            acc[mt][nt] = (floatx4){0.f, 0.f, 0.f, 0.f};

    const bf16x8* Pbase = (const bf16x8*)Pperm + (size_t)(pg * 16) * 2048; // 2048 = 16384/8

    for (int pp = 0; pp < 16; ++pp) {
        const bf16x8* Pp = Pbase + (size_t)pp * 2048;
        floatx4 S[2][2];
#pragma unroll
        for (int mt = 0; mt < 2; ++mt)
#pragma unroll
            for (int nt = 0; nt < 2; ++nt)
                S[mt][nt] = (floatx4){0.f, 0.f, 0.f, 0.f};

#pragma unroll
        for (int ks = 0; ks < 4; ++ks) {
            bf16x8 Bf[2];
#pragma unroll
            for (int nt = 0; nt < 2; ++nt) {
                const int c = w * 2 + nt;
                Bf[nt] = Pp[(size_t)(ks * 8 + c) * 64 + L];
            }
#pragma unroll
            for (int mt = 0; mt < 2; ++mt)
#pragma unroll
                for (int nt = 0; nt < 2; ++nt)
                    S[mt][nt] = __builtin_amdgcn_mfma_f32_16x16x32_bf16(
                        A[mt][ks], Bf[nt], S[mt][nt], 0, 0, 0);
        }
        // fold Zi[b,p] (fp32) into the output accumulator
#pragma unroll
        for (int mt = 0; mt < 2; ++mt) {
            const floatx4 zi = *(const floatx4*)&sZiT[pp][mt * 16 + quad * 4];
#pragma unroll
            for (int nt = 0; nt < 2; ++nt)
                acc[mt][nt] += zi * S[mt][nt];
        }
    }

    // epilogue: atomic accumulate into T (8 p-groups collide per element)
#pragma unroll
    for (int mt = 0; mt < 2; ++mt)
#pragma unroll
        for (int nt = 0; nt < 2; ++nt)
#pragma unroll
            for (int r = 0; r < 4; ++r) {
                const int row = b0 + mt * 16 + quad * 4 + r;
                const int col = (w * 2 + nt) * 16 + lo;
                atomicAdd(&T[(size_t)row * H_ + col], acc[mt][nt][r]);
            }
}

// ---------------------------------------------------------------------------
// column stats (sum, sumsq) of a (B,H) matrix into stats[0:128], stats[128:256]
__global__ void k_colstats(const float* __restrict__ A, float* __restrict__ stats) {
    const int t = threadIdx.x;
    const int k = t & 127, half = t >> 7;
    const int r0 = blockIdx.x * 32;
    float sum = 0.f, ssq = 0.f;
    for (int i = half; i < 32; i += 2) {
        const float v = A[(size_t)(r0 + i) * H_ + k];
        sum += v; ssq += v * v;
    }
    __shared__ float ssum[256], sssq[256];
    ssum[t] = sum; sssq[t] = ssq;
    __syncthreads();
    if (half == 0) {
        atomicAdd(&stats[k],       ssum[t] + ssum[t + 128]);
        atomicAdd(&stats[128 + k], sssq[t] + sssq[t + 128]);
    }
}

// ---------------------------------------------------------------------------
// BN apply -> new Zi; Y += Zi/RANK; zero T for the next rank's atomics
__global__ void k_bn_apply(float* __restrict__ T, const float* __restrict__ stats,
                           const float* __restrict__ g, const float* __restrict__ bta,
                           float* __restrict__ Zi, float* __restrict__ Y) {
    const int i = blockIdx.x * 256 + threadIdx.x;
    const int k = i & 127;
    const float m  = stats[k] * (1.f / B_);
    const float v  = stats[128 + k] * (1.f / B_) - m * m;
    const float rs = rsqrtf(v + EPS_);
    const float z  = (T[i] - m) * rs * g[k] + bta[k];
    T[i]  = 0.f;
    Zi[i] = z;
    Y[i] += z * (1.f / RANK_);
}

// ---------------------------------------------------------------------------
// out = relu(relu(BN(Y)@W3 + b3) + R2)
__global__ void k_out(const float* __restrict__ Y, const float* __restrict__ ystats,
                      const float* __restrict__ gy, const float* __restrict__ by,
                      const float* __restrict__ W3, const float* __restrict__ b3,
                      const float* __restrict__ R2, float* __restrict__ out) {
    __shared__ float sy[H_];
    const int b = blockIdx.x, t = threadIdx.x;
    const float m  = ystats[t] * (1.f / B_);
    const float v  = ystats[128 + t] * (1.f / B_) - m * m;
    const float rs = rsqrtf(v + EPS_);
    sy[t] = (Y[(size_t)b * H_ + t] - m) * rs * gy[t] + by[t];
    __syncthreads();
    float s = 0.f;
#pragma unroll 8
    for (int h = 0; h < H_; ++h)
        s = fmaf(sy[h], W3[h * H_ + t], s);
    const float r = fmaxf(s + b3[t], 0.f) + R2[(size_t)b * H_ + t];
    out[(size_t)b * H_ + t] = fmaxf(r, 0.f);
}

// ---------------------------------------------------------------------------
extern "C" void kernel_launch(void* const* d_in, const int* in_sizes, int n_in,
                              void* d_out, int out_size, void* d_ws, size_t ws_size,
                              hipStream_t stream) {
    const float* X  = (const float*)d_in[0];
    const float* W1 = (const float*)d_in[1];
    const float* b1 = (const float*)d_in[2];
    const float* W2 = (const float*)d_in[3];
    const float* b2 = (const float*)d_in[4];
    const float* W3 = (const float*)d_in[5];
    const float* b3 = (const float*)d_in[6];
    const float* P  = (const float*)d_in[7];
    const float* gz = (const float*)d_in[8];
    const float* bz = (const float*)d_in[9];
    const float* gy = (const float*)d_in[10];
    const float* by = (const float*)d_in[11];
    float* out = (float*)d_out;

    const size_t rankElems = (size_t)H_ * H_ * H_;          // 2,097,152
    const size_t nonP_bytes = (size_t)5 * B_ * H_ * 4       // T,Z,Zi,R2,Y
                            + (RANK_ + 1) * 256 * 4         // stats
                            + (size_t)B_ * H_ * 2;          // Zbf
    const bool fullA = ws_size >= (size_t)RANK_ * rankElems * 2 + nonP_bytes + 256;
    const size_t permElems = fullA ? (size_t)RANK_ * rankElems : 2 * rankElems;

    char* wsb = (char*)d_ws;
    __bf16* Pperm = (__bf16*)wsb;                    wsb += permElems * 2;
    float* T      = (float*)wsb;                     wsb += (size_t)B_ * H_ * 4;
    float* Z      = (float*)wsb;                     wsb += (size_t)B_ * H_ * 4;
    float* Zi     = (float*)wsb;                     wsb += (size_t)B_ * H_ * 4;
    float* R2     = (float*)wsb;                     wsb += (size_t)B_ * H_ * 4;
    float* Y      = (float*)wsb;                     wsb += (size_t)B_ * H_ * 4;
    float* stats  = (float*)wsb;                     wsb += (RANK_ + 1) * 256 * 4;
    __bf16* Zbf   = (__bf16*)wsb;

    k_init<<<(B_ * H_ + 255) / 256, 256, 0, stream>>>(Y, T, stats);
    k_in_proj<<<B_, H_, 0, stream>>>(X, W1, b1, W2, b2, Z, Zi, R2, Zbf);

    if (fullA)
        for (int r = 0; r < RANK_; ++r)
            k_pconv<<<H_, 256, 0, stream>>>(P + r * rankElems, Pperm + r * rankElems);

    for (int r = 0; r < RANK_; ++r) {
        __bf16* Pr = fullA ? (Pperm + r * rankElems) : (Pperm + (r & 1) * rankElems);
        if (!fullA)
            k_pconv<<<H_, 256, 0, stream>>>(P + r * rankElems, Pr);
        k_quad_mfma<<<dim3(B_ / 32, 8), 256, 0, stream>>>(Pr, Zbf, Zi, T);
        k_colstats<<<64, 256, 0, stream>>>(T, stats + r * 256);
        k_bn_apply<<<(B_ * H_) / 256, 256, 0, stream>>>(T, stats + r * 256, gz, bz, Zi, Y);
    }

    k_colstats<<<64, 256, 0, stream>>>(Y, stats + RANK_ * 256);
    k_out<<<B_, H_, 0, stream>>>(Y, stats + RANK_ * 256, gy, by, W3, b3, R2, out);
}

// Round 3
// 423.988 us; speedup vs baseline: 3.1759x; 1.0476x over previous
//
#include <hip/hip_runtime.h>

typedef __bf16 bf16x8 __attribute__((ext_vector_type(8)));
typedef float  floatx4 __attribute__((ext_vector_type(4)));

constexpr int B_    = 2048;
constexpr int NIN   = 256;
constexpr int H_    = 128;
constexpr int RANK_ = 8;
constexpr float EPS_ = 1e-5f;

constexpr int NP  = 8;                 // p's per group
constexpr int NPG = H_ / NP;           // 16 p-groups
constexpr int MT  = 64;                // rows per block

// ---------------------------------------------------------------------------
// init: zero Y and stats (T is fully overwritten by reduce each rank)
__global__ void k_init(float* __restrict__ Y, float* __restrict__ stats) {
    int i = blockIdx.x * 256 + threadIdx.x;
    if (i < B_ * H_) Y[i] = 0.f;
    if (i < (RANK_ + 1) * 256) stats[i] = 0.f;
}

// ---------------------------------------------------------------------------
// Zi = relu(X@W1+b1) (fp32 + bf16); R2 = relu(X@W2+b2)
__global__ void k_in_proj(const float* __restrict__ X,
                          const float* __restrict__ W1, const float* __restrict__ b1,
                          const float* __restrict__ W2, const float* __restrict__ b2,
                          float* __restrict__ Zi, float* __restrict__ R2,
                          __bf16* __restrict__ Zbf) {
    __shared__ float sx[NIN];
    const int b = blockIdx.x, t = threadIdx.x;
    sx[t]      = X[b * NIN + t];
    sx[t + H_] = X[b * NIN + H_ + t];
    __syncthreads();
    float s1 = 0.f, s2 = 0.f;
#pragma unroll 8
    for (int i = 0; i < NIN; ++i) {
        const float x = sx[i];
        s1 = fmaf(x, W1[i * H_ + t], s1);
        s2 = fmaf(x, W2[i * H_ + t], s2);
    }
    const float z = fmaxf(s1 + b1[t], 0.f);
    const float r = fmaxf(s2 + b2[t], 0.f);
    Zi[b * H_ + t]  = z;
    R2[b * H_ + t]  = r;
    Zbf[b * H_ + t] = (__bf16)z;
}

// ---------------------------------------------------------------------------
// Convert P[r][p][q][k] (fp32) into MFMA-B-fragment-ordered bf16, all ranks.
// dst elem: (((p*4 + s)*8 + c)*64 + L)*8 + j  <-  P[p][s*32+(L>>4)*8+j][c*16+(L&15)]
// grid: (128 p, 8 r), 256 threads.
__global__ void k_pconv(const float* __restrict__ Psrc, __bf16* __restrict__ dst) {
    const int p = blockIdx.x, r = blockIdx.y, t = threadIdx.x;
    const int s = t >> 6, L = t & 63, quad = L >> 4, lo = L & 15;
    const size_t rb = (size_t)r * H_ * H_ * H_;
    const float* Pp = Psrc + rb + (size_t)p * (H_ * H_);
    __bf16* dp = dst + rb + (size_t)p * (H_ * H_);
#pragma unroll
    for (int c = 0; c < 8; ++c) {
        __bf16 v[8];
#pragma unroll
        for (int j = 0; j < 8; ++j) {
            const int q = s * 32 + quad * 8 + j;
            const int k = c * 16 + lo;
            v[j] = (__bf16)Pp[q * H_ + k];
        }
        *(bf16x8*)(dp + (((size_t)(s * 8 + c)) * 64 + L) * 8) = *(const bf16x8*)v;
    }
}

// ---------------------------------------------------------------------------
// Quadratic: Tpart[pg][b][k] = sum_{p in group} Zi[b,p] * (Z @ P[p])[b,k]
// grid (32 m-tiles of 64 rows, 16 p-groups of 8), block 256 (4 waves).
// Wave w owns cols [w*32, w*32+32); A (Z rows) register-resident, p-invariant.
__global__ __launch_bounds__(256, 2)
void k_quad_mfma(const __bf16* __restrict__ Pperm,   // rank base, frag-ordered
                 const __bf16* __restrict__ Zbf,
                 const float* __restrict__ Zi,
                 float* __restrict__ Tpart) {
    const int mx = blockIdx.x;
    const int pg = blockIdx.y;
    const int t  = threadIdx.x;
    const int w  = t >> 6, L = t & 63;
    const int quad = L >> 4, lo = L & 15;
    const int b0 = mx * MT;

    __shared__ float sZiT[NP][MT];      // [p-local][row]
    for (int e = t; e < NP * MT; e += 256) {
        const int pp = e & (NP - 1), row = e >> 3;
        sZiT[pp][row] = Zi[(size_t)(b0 + row) * H_ + pg * NP + pp];
    }

    bf16x8 A[4][4];                     // [mt][ks]
#pragma unroll
    for (int mt = 0; mt < 4; ++mt)
#pragma unroll
        for (int ks = 0; ks < 4; ++ks)
            A[mt][ks] = *(const bf16x8*)(Zbf + (size_t)(b0 + mt * 16 + lo) * H_ + ks * 32 + quad * 8);
    __syncthreads();

    floatx4 acc[4][2];
#pragma unroll
    for (int mt = 0; mt < 4; ++mt)
#pragma unroll
        for (int nt = 0; nt < 2; ++nt)
            acc[mt][nt] = (floatx4){0.f, 0.f, 0.f, 0.f};

    const bf16x8* Pbase = (const bf16x8*)Pperm + (size_t)(pg * NP) * 2048; // 2048 frags per p

    for (int pp = 0; pp < NP; ++pp) {
        const bf16x8* Pp = Pbase + (size_t)pp * 2048;
        floatx4 S[4][2];
#pragma unroll
        for (int mt = 0; mt < 4; ++mt)
#pragma unroll
            for (int nt = 0; nt < 2; ++nt)
                S[mt][nt] = (floatx4){0.f, 0.f, 0.f, 0.f};

#pragma unroll
        for (int ks = 0; ks < 4; ++ks) {
            bf16x8 Bf[2];
#pragma unroll
            for (int nt = 0; nt < 2; ++nt)
                Bf[nt] = Pp[(size_t)(ks * 8 + w * 2 + nt) * 64 + L];
#pragma unroll
            for (int mt = 0; mt < 4; ++mt)
#pragma unroll
                for (int nt = 0; nt < 2; ++nt)
                    S[mt][nt] = __builtin_amdgcn_mfma_f32_16x16x32_bf16(
                        A[mt][ks], Bf[nt], S[mt][nt], 0, 0, 0);
        }
#pragma unroll
        for (int mt = 0; mt < 4; ++mt) {
            const floatx4 zi = *(const floatx4*)&sZiT[pp][mt * 16 + quad * 4];
#pragma unroll
            for (int nt = 0; nt < 2; ++nt)
                acc[mt][nt] += zi * S[mt][nt];
        }
    }

    // epilogue: plain stores into this p-group's partial slice
    float* Tp = Tpart + (size_t)pg * (B_ * H_);
#pragma unroll
    for (int mt = 0; mt < 4; ++mt)
#pragma unroll
        for (int nt = 0; nt < 2; ++nt) {
            const int col = (w * 2 + nt) * 16 + lo;
#pragma unroll
            for (int r = 0; r < 4; ++r) {
                const int row = b0 + mt * 16 + quad * 4 + r;
                Tp[(size_t)row * H_ + col] = acc[mt][nt][r];
            }
        }
}

// ---------------------------------------------------------------------------
// T = sum over 16 partials; column sum/sumsq into stats (atomics, 16K total).
__global__ void k_reduce_stats(const float* __restrict__ Tpart,
                               float* __restrict__ T, float* __restrict__ stats) {
    const int t = threadIdx.x;
    const int k = t & 127, half = t >> 7;
    const int r0 = blockIdx.x * 32;
    float sum = 0.f, ssq = 0.f;
    for (int i = half; i < 32; i += 2) {
        const int b = r0 + i;
        float v = 0.f;
#pragma unroll
        for (int c = 0; c < NPG; ++c)
            v += Tpart[((size_t)c * B_ + b) * H_ + k];
        T[(size_t)b * H_ + k] = v;
        sum += v;
        ssq += v * v;
    }
    __shared__ float ssum[256], sssq[256];
    ssum[t] = sum; sssq[t] = ssq;
    __syncthreads();
    if (half == 0) {
        atomicAdd(&stats[k],       ssum[t] + ssum[t + 128]);
        atomicAdd(&stats[128 + k], sssq[t] + sssq[t + 128]);
    }
}

// ---------------------------------------------------------------------------
// BN apply -> new Zi (fp32); Y += Zi/RANK
__global__ void k_bn_apply(const float* __restrict__ T, const float* __restrict__ stats,
                           const float* __restrict__ g, const float* __restrict__ bta,
                           float* __restrict__ Zi, float* __restrict__ Y) {
    const int i = blockIdx.x * 256 + threadIdx.x;
    const int k = i & 127;
    const float m  = stats[k] * (1.f / B_);
    const float v  = stats[128 + k] * (1.f / B_) - m * m;
    const float rs = rsqrtf(v + EPS_);
    const float z  = (T[i] - m) * rs * g[k] + bta[k];
    Zi[i] = z;
    Y[i] += z * (1.f / RANK_);
}

// ---------------------------------------------------------------------------
// column stats of Y
__global__ void k_colstats(const float* __restrict__ A, float* __restrict__ stats) {
    const int t = threadIdx.x;
    const int k = t & 127, half = t >> 7;
    const int r0 = blockIdx.x * 32;
    float sum = 0.f, ssq = 0.f;
    for (int i = half; i < 32; i += 2) {
        const float v = A[(size_t)(r0 + i) * H_ + k];
        sum += v; ssq += v * v;
    }
    __shared__ float ssum[256], sssq[256];
    ssum[t] = sum; sssq[t] = ssq;
    __syncthreads();
    if (half == 0) {
        atomicAdd(&stats[k],       ssum[t] + ssum[t + 128]);
        atomicAdd(&stats[128 + k], sssq[t] + sssq[t + 128]);
    }
}

// ---------------------------------------------------------------------------
// out = relu(relu(BN(Y)@W3 + b3) + R2)
__global__ void k_out(const float* __restrict__ Y, const float* __restrict__ ystats,
                      const float* __restrict__ gy, const float* __restrict__ by,
                      const float* __restrict__ W3, const float* __restrict__ b3,
                      const float* __restrict__ R2, float* __restrict__ out) {
    __shared__ float sy[H_];
    const int b = blockIdx.x, t = threadIdx.x;
    const float m  = ystats[t] * (1.f / B_);
    const float v  = ystats[128 + t] * (1.f / B_) - m * m;
    const float rs = rsqrtf(v + EPS_);
    sy[t] = (Y[(size_t)b * H_ + t] - m) * rs * gy[t] + by[t];
    __syncthreads();
    float s = 0.f;
#pragma unroll 8
    for (int h = 0; h < H_; ++h)
        s = fmaf(sy[h], W3[h * H_ + t], s);
    const float r = fmaxf(s + b3[t], 0.f) + R2[(size_t)b * H_ + t];
    out[(size_t)b * H_ + t] = fmaxf(r, 0.f);
}

// ---------------------------------------------------------------------------
extern "C" void kernel_launch(void* const* d_in, const int* in_sizes, int n_in,
                              void* d_out, int out_size, void* d_ws, size_t ws_size,
                              hipStream_t stream) {
    const float* X  = (const float*)d_in[0];
    const float* W1 = (const float*)d_in[1];
    const float* b1 = (const float*)d_in[2];
    const float* W2 = (const float*)d_in[3];
    const float* b2 = (const float*)d_in[4];
    const float* W3 = (const float*)d_in[5];
    const float* b3 = (const float*)d_in[6];
    const float* P  = (const float*)d_in[7];
    const float* gz = (const float*)d_in[8];
    const float* bz = (const float*)d_in[9];
    const float* gy = (const float*)d_in[10];
    const float* by = (const float*)d_in[11];
    float* out = (float*)d_out;

    const size_t rankElems = (size_t)H_ * H_ * H_;          // 2,097,152

    char* wsb = (char*)d_ws;
    __bf16* Pperm = (__bf16*)wsb;  wsb += (size_t)RANK_ * rankElems * 2;   // 33.5 MB
    float* Tpart  = (float*)wsb;   wsb += (size_t)NPG * B_ * H_ * 4;       // 16 MB
    float* T      = (float*)wsb;   wsb += (size_t)B_ * H_ * 4;
    float* Zi     = (float*)wsb;   wsb += (size_t)B_ * H_ * 4;
    float* R2     = (float*)wsb;   wsb += (size_t)B_ * H_ * 4;
    float* Y      = (float*)wsb;   wsb += (size_t)B_ * H_ * 4;
    float* stats  = (float*)wsb;   wsb += (RANK_ + 1) * 256 * 4;
    __bf16* Zbf   = (__bf16*)wsb;

    k_init<<<(B_ * H_ + 255) / 256, 256, 0, stream>>>(Y, stats);
    k_in_proj<<<B_, H_, 0, stream>>>(X, W1, b1, W2, b2, Zi, R2, Zbf);
    k_pconv<<<dim3(H_, RANK_), 256, 0, stream>>>(P, Pperm);

    for (int r = 0; r < RANK_; ++r) {
        const __bf16* Pr = Pperm + (size_t)r * rankElems;
        k_quad_mfma<<<dim3(B_ / MT, NPG), 256, 0, stream>>>(Pr, Zbf, Zi, Tpart);
        k_reduce_stats<<<64, 256, 0, stream>>>(Tpart, T, stats + r * 256);
        k_bn_apply<<<(B_ * H_) / 256, 256, 0, stream>>>(T, stats + r * 256, gz, bz, Zi, Y);
    }

    k_colstats<<<64, 256, 0, stream>>>(Y, stats + RANK_ * 256);
    k_out<<<B_, H_, 0, stream>>>(Y, stats + RANK_ * 256, gy, by, W3, b3, R2, out);
}